// Round 6
// baseline (354.410 us; speedup 1.0000x reference)
//
#include <hip/hip_runtime.h>
#include <hip/hip_bf16.h>

typedef __attribute__((ext_vector_type(4))) float  f32x4;
typedef __attribute__((ext_vector_type(8))) _Float16 h16x8;

#define EMB 128
#define NSEQ 4096
#define NB 8
#define SCALE 0.08838834764831845f   // 1/sqrt(128)
#define QSC   (0.08838834764831845f * 1.44269504f)   // SCALE * log2(e)
#define NT    (NSEQ / 64)

// ---------------- prep: hi/lo split transposed weights ----------------
__global__ void prep_w(const float* __restrict__ wq, const float* __restrict__ wk,
                       const float* __restrict__ wv, _Float16* __restrict__ whiT,
                       _Float16* __restrict__ wloT) {
    int idx = blockIdx.x * 256 + threadIdx.x;          // 3*128*128 = 49152
    if (idx >= 3 * EMB * EMB) return;
    int widx = idx >> 14;
    int rem  = idx & 16383;
    int d = rem >> 7;
    int e = rem & 127;
    const float* w = (widx == 0) ? wq : (widx == 1) ? wk : wv;
    float v = w[d * 128 + e];
    _Float16 hi = (_Float16)v;
    _Float16 lo = (_Float16)(v - (float)hi);
    whiT[(size_t)widx * 16384 + (size_t)e * 128 + d] = hi;
    wloT[(size_t)widx * 16384 + (size_t)e * 128 + d] = lo;
}

// ---------------- QKV projection, grid split over widx ----------------
// q: [tok][128] f16 = (Q - c_q)*QSC ; k: [tok][128] f16 = K - c_k ;
// aq[tok] = c_q*128*QSC ; ck[tok] = c_k ; vT: [b][e][n] f16.
__global__ __launch_bounds__(256) void qkv_proj(const float* __restrict__ x,
                                                const _Float16* __restrict__ whiT,
                                                const _Float16* __restrict__ wloT,
                                                _Float16* __restrict__ q,
                                                _Float16* __restrict__ k,
                                                _Float16* __restrict__ vT,
                                                float* __restrict__ aq,
                                                float* __restrict__ ck) {
    const int widx = blockIdx.x >> 9;          // 0,1,2
    const int blk  = blockIdx.x & 511;
    const int lane = threadIdx.x & 63;
    const int wave = threadIdx.x >> 6;
    const int g    = lane >> 4;
    const int lr   = lane & 15;
    const int rb   = blk * 64 + wave * 16;

    h16x8 xhi[4], xlo[4];
    {
        const float* xrow = x + (size_t)(rb + lr) * EMB;
        #pragma unroll
        for (int kc = 0; kc < 4; ++kc) {
            const float* p = xrow + kc * 32 + g * 8;
            h16x8 ah, al;
            #pragma unroll
            for (int j = 0; j < 8; ++j) {
                float v = p[j];
                _Float16 h = (_Float16)v;
                ah[j] = h;
                al[j] = (_Float16)(v - (float)h);
            }
            xhi[kc] = ah;
            if (widx < 2) xlo[kc] = al;
        }
    }

    const int b  = rb >> 12;
    const int n0 = rb & 4095;

    f32x4 acc[8];
    #pragma unroll
    for (int ct = 0; ct < 8; ++ct) acc[ct] = (f32x4){0.f, 0.f, 0.f, 0.f};

    const _Float16* wh = whiT + (size_t)widx * 16384;
    const _Float16* wl = wloT + (size_t)widx * 16384;
    #pragma unroll
    for (int kc = 0; kc < 4; ++kc) {
        #pragma unroll
        for (int ct = 0; ct < 8; ++ct) {
            size_t off = (size_t)(ct * 16 + lr) * 128 + kc * 32 + g * 8;
            h16x8 bh = *(const h16x8*)(wh + off);
            acc[ct] = __builtin_amdgcn_mfma_f32_16x16x32_f16(xhi[kc], bh, acc[ct], 0, 0, 0);
            if (widx < 2) {
                h16x8 bl = *(const h16x8*)(wl + off);
                acc[ct] = __builtin_amdgcn_mfma_f32_16x16x32_f16(xlo[kc], bh, acc[ct], 0, 0, 0);
                acc[ct] = __builtin_amdgcn_mfma_f32_16x16x32_f16(xhi[kc], bl, acc[ct], 0, 0, 0);
            }
        }
    }

    if (widx < 2) {
        float c[4];
        #pragma unroll
        for (int r = 0; r < 4; ++r) {
            float rs = 0.f;
            #pragma unroll
            for (int ct = 0; ct < 8; ++ct) rs += acc[ct][r];
            #pragma unroll
            for (int off = 8; off; off >>= 1) rs += __shfl_xor(rs, off);
            c[r] = rs * (1.0f / 128.0f);
        }
        if (widx == 0) {
            #pragma unroll
            for (int ct = 0; ct < 8; ++ct)
                #pragma unroll
                for (int r = 0; r < 4; ++r) {
                    size_t row = rb + g * 4 + r;
                    q[row * 128 + ct * 16 + lr] = (_Float16)((acc[ct][r] - c[r]) * QSC);
                }
            if (lr == 0) {
                #pragma unroll
                for (int r = 0; r < 4; ++r) aq[rb + g * 4 + r] = c[r] * 128.0f * QSC;
            }
        } else {
            #pragma unroll
            for (int ct = 0; ct < 8; ++ct)
                #pragma unroll
                for (int r = 0; r < 4; ++r) {
                    size_t row = rb + g * 4 + r;
                    k[row * 128 + ct * 16 + lr] = (_Float16)(acc[ct][r] - c[r]);
                }
            if (lr == 0) {
                #pragma unroll
                for (int r = 0; r < 4; ++r) ck[rb + g * 4 + r] = c[r];
            }
        }
    } else {
        #pragma unroll
        for (int ct = 0; ct < 8; ++ct)
            #pragma unroll
            for (int r = 0; r < 4; ++r) {
                int e  = ct * 16 + lr;
                int nn = n0 + g * 4 + r;
                vT[((size_t)b * EMB + e) * NSEQ + nn] = (_Float16)acc[ct][r];
            }
    }
}

// ---------------- flash attention: swapped QK^T, permuted K slots, in-reg P ----------------
// LDS slot for global kv row: sigma(kv) = (2*(kv>>5) + ((kv>>2)&1))*16 + ((kv>>3)&3)*4 + (kv&3)
// Then lane (g,lr) owns, via S^T = mfma(K,Q), exactly kv in [w*32+g*8, w*32+g*8+7] for w=0,1
// -> P feeds PV's A-fragment directly, no LDS round-trip, no cross-lane exchange.
__global__ __launch_bounds__(256) void flash(const _Float16* __restrict__ q,
                                             const _Float16* __restrict__ k,
                                             const _Float16* __restrict__ vT,
                                             const float* __restrict__ aq,
                                             const float* __restrict__ ck,
                                             float* __restrict__ out) {
    __shared__ __align__(16) char KsB[2][16384];   // 64 slots x 256 B, XOR-swizzled

    // bijective XCD swizzle: each XCD owns one batch
    const int bp  = blockIdx.x;
    const int bid = (bp & 7) * 64 + (bp >> 3);

    const int lane = threadIdx.x & 63;
    const int wave = threadIdx.x >> 6;
    const int g    = lane >> 4;
    const int lr   = lane & 15;
    const int b    = bid >> 6;
    const int qt   = bid & 63;
    const size_t qtok = (size_t)b * NSEQ + qt * 64 + wave * 16;

    const _Float16* kbat = k  + (size_t)b * NSEQ * EMB;
    const _Float16* vbat = vT + (size_t)b * EMB * NSEQ;
    const float*    ckb  = ck + (size_t)b * NSEQ;

    // Q fragments (QSC folded); per-lane q-row for softmax is q = lr
    h16x8 qf[4];
    #pragma unroll
    for (int kc = 0; kc < 4; ++kc)
        qf[kc] = *(const h16x8*)(q + (qtok + lr) * 128 + kc * 32 + g * 8);
    const float aqv = aq[qtok + lr];

    // K staging geometry: global row r64 -> permuted LDS slot
    const int r64   = wave * 16 + (lane >> 2);
    const int kcolB = (lane & 3) * 64;
    const int kslot = ((r64 >> 5) * 2 + ((r64 >> 2) & 1)) * 16 + (((r64 >> 3) & 3) << 2) + (r64 & 3);
    const char* kbase = (const char*)(kbat + (size_t)r64 * EMB) + kcolB;
    const int kdst = kslot * 256;
    const int kswz = (kslot & 15) << 4;

    h16x8 stK[4];
    // prologue: stage tile 0
    #pragma unroll
    for (int i = 0; i < 4; ++i) stK[i] = *(const h16x8*)(kbase + i * 16);
    #pragma unroll
    for (int i = 0; i < 4; ++i)
        *(h16x8*)(KsB[0] + kdst + ((kcolB + i * 16) ^ kswz)) = stK[i];
    __syncthreads();

    f32x4 o[8];
    #pragma unroll
    for (int ct = 0; ct < 8; ++ct) o[ct] = (f32x4){0.f, 0.f, 0.f, 0.f};
    float m = -1e30f;
    float l = 0.f;     // per-lane partial row sum (q = lr)

    int cur = 0;
    for (int t = 0; t < NT; ++t) {
        // (1) V fragments for THIS tile — issued FIRST so PV's wait leaves the
        //     K-prefetch (issued after) in flight (counted vmcnt).
        h16x8 vreg[16];
        #pragma unroll
        for (int ct = 0; ct < 8; ++ct)
            #pragma unroll
            for (int w = 0; w < 2; ++w)
                vreg[ct * 2 + w] = *(const h16x8*)(vbat + (size_t)(ct * 16 + lr) * NSEQ
                                                   + t * 64 + w * 32 + g * 8);

        // (2) rank-1 coefficients, permuted to match slot ownership
        f32x4 ckt[4];
        #pragma unroll
        for (int ct = 0; ct < 4; ++ct)
            ckt[ct] = *(const f32x4*)(ckb + t * 64 + (ct >> 1) * 32 + (ct & 1) * 4 + g * 8);

        // (3) next K tile's staging loads (drained only at the ds_write below)
        const int tn = (t + 1) & (NT - 1);
        #pragma unroll
        for (int i = 0; i < 4; ++i)
            stK[i] = *(const h16x8*)(kbase + (size_t)tn * 16384 + i * 16);

        // (4) S^T = mfma(K, Q): lane holds S[q=lr][kv = (ct>>1)*32 + g*8 + (ct&1)*4 + r]
        const char* Kb = KsB[cur];
        f32x4 s[4];
        __builtin_amdgcn_s_setprio(1);
        #pragma unroll
        for (int ct = 0; ct < 4; ++ct) {
            f32x4 acc = (f32x4){0.f, 0.f, 0.f, 0.f};
            #pragma unroll
            for (int kc = 0; kc < 4; ++kc) {
                h16x8 kb = *(const h16x8*)(Kb + (ct * 16 + lr) * 256 + ((kc * 64 + g * 16) ^ (lr << 4)));
                acc = __builtin_amdgcn_mfma_f32_16x16x32_f16(kb, qf[kc], acc, 0, 0, 0);
            }
            #pragma unroll
            for (int r = 0; r < 4; ++r) acc[r] += aqv * ckt[ct][r];
            s[ct] = acc;
        }
        __builtin_amdgcn_s_setprio(0);

        // (5) softmax (log2 domain), per-lane scalar state for q = lr
        float tm = s[0][0];
        #pragma unroll
        for (int ct = 0; ct < 4; ++ct)
            #pragma unroll
            for (int r = 0; r < 4; ++r) tm = fmaxf(tm, s[ct][r]);
        tm = fmaxf(tm, __shfl_xor(tm, 16));
        tm = fmaxf(tm, __shfl_xor(tm, 32));
        if (__any(tm > m + 11.544f)) {          // defer-max (8 nats in log2)
            float mn = fmaxf(m, tm);
            float sc = exp2f(m - mn);
            m = mn;
            l *= sc;
            float oscr[4];
            #pragma unroll
            for (int r = 0; r < 4; ++r)
                oscr[r] = __shfl(sc, (lane & 48) | (g * 4 + r));
            #pragma unroll
            for (int ct = 0; ct < 8; ++ct)
                #pragma unroll
                for (int r = 0; r < 4; ++r) o[ct][r] *= oscr[r];
        }
        #pragma unroll
        for (int ct = 0; ct < 4; ++ct)
            #pragma unroll
            for (int r = 0; r < 4; ++r) {
                float pv = exp2f(s[ct][r] - m);
                s[ct][r] = pv;
                l += pv;
            }

        // (6) pack P directly into PV A-fragments (lane-local, no LDS)
        h16x8 pa[2];
        #pragma unroll
        for (int w = 0; w < 2; ++w) {
            h16x8 t8;
            #pragma unroll
            for (int j = 0; j < 4; ++j) {
                t8[j]     = (_Float16)s[2 * w][j];
                t8[4 + j] = (_Float16)s[2 * w + 1][j];
            }
            pa[w] = t8;
        }

        // (7) O += P V  (V frags in registers; waits vmcnt leaving stK in flight)
        __builtin_amdgcn_s_setprio(1);
        #pragma unroll
        for (int ct = 0; ct < 8; ++ct) {
            #pragma unroll
            for (int w = 0; w < 2; ++w)
                o[ct] = __builtin_amdgcn_mfma_f32_16x16x32_f16(pa[w], vreg[ct * 2 + w], o[ct], 0, 0, 0);
        }
        __builtin_amdgcn_s_setprio(0);

        // (8) write next K tile into the other buffer; one barrier per tile
        {
            char* kw = (char*)KsB[cur ^ 1];
            #pragma unroll
            for (int i = 0; i < 4; ++i)
                *(h16x8*)(kw + kdst + ((kcolB + i * 16) ^ kswz)) = stK[i];
        }
        __syncthreads();
        cur ^= 1;
    }

    // epilogue: full row sum for q=lr, then broadcast 1/l to the O-row owners
    l += __shfl_xor(l, 16);
    l += __shfl_xor(l, 32);
    float linv = 1.0f / l;
    float lrw[4];
    #pragma unroll
    for (int r = 0; r < 4; ++r)
        lrw[r] = __shfl(linv, (lane & 48) | (g * 4 + r));
    #pragma unroll
    for (int ct = 0; ct < 8; ++ct)
        #pragma unroll
        for (int r = 0; r < 4; ++r) {
            size_t row = qtok + g * 4 + r;
            out[row * EMB + ct * 16 + lr] = o[ct][r] * lrw[r];
        }
}

extern "C" void kernel_launch(void* const* d_in, const int* in_sizes, int n_in,
                              void* d_out, int out_size, void* d_ws, size_t ws_size,
                              hipStream_t stream) {
    const float* x  = (const float*)d_in[0];
    const float* wq = (const float*)d_in[1];
    const float* wk = (const float*)d_in[2];
    const float* wv = (const float*)d_in[3];

    char* ws = (char*)d_ws;
    _Float16* q    = (_Float16*)(ws);                          // 8 MB
    _Float16* kk   = (_Float16*)(ws + 8388608);                // 8 MB
    _Float16* vT   = (_Float16*)(ws + 16777216);               // 8 MB
    float*    aq   = (float*)   (ws + 25165824);               // 128 KB
    float*    ck   = (float*)   (ws + 25296896);               // 128 KB
    _Float16* whiT = (_Float16*)(ws + 25427968);               // 96 KB
    _Float16* wloT = (_Float16*)(ws + 25526272);               // 96 KB

    prep_w<<<192, 256, 0, stream>>>(wq, wk, wv, whiT, wloT);
    qkv_proj<<<1536, 256, 0, stream>>>(x, whiT, wloT, q, kk, vT, aq, ck);
    flash<<<512, 256, 0, stream>>>(q, kk, vT, aq, ck, (float*)d_out);
}

// Round 7
// 181.561 us; speedup vs baseline: 1.9520x; 1.9520x over previous
//
#include <hip/hip_runtime.h>
#include <hip/hip_bf16.h>

typedef __attribute__((ext_vector_type(4))) float  f32x4;
typedef __attribute__((ext_vector_type(8))) _Float16 h16x8;

#define EMB 128
#define NSEQ 4096
#define NB 8
#define SCALE 0.08838834764831845f   // 1/sqrt(128)
#define QSC   (0.08838834764831845f * 1.44269504f)   // SCALE * log2(e)
#define NT    (NSEQ / 64)

// ---------------- prep: hi/lo split transposed weights ----------------
__global__ void prep_w(const float* __restrict__ wq, const float* __restrict__ wk,
                       const float* __restrict__ wv, _Float16* __restrict__ whiT,
                       _Float16* __restrict__ wloT) {
    int idx = blockIdx.x * 256 + threadIdx.x;          // 3*128*128 = 49152
    if (idx >= 3 * EMB * EMB) return;
    int widx = idx >> 14;
    int rem  = idx & 16383;
    int d = rem >> 7;
    int e = rem & 127;
    const float* w = (widx == 0) ? wq : (widx == 1) ? wk : wv;
    float v = w[d * 128 + e];
    _Float16 hi = (_Float16)v;
    _Float16 lo = (_Float16)(v - (float)hi);
    whiT[(size_t)widx * 16384 + (size_t)e * 128 + d] = hi;
    wloT[(size_t)widx * 16384 + (size_t)e * 128 + d] = lo;
}

// ---------------- QKV projection, grid split over widx ----------------
// q: [tok][128] f16 = (Q - c_q)*QSC ; k: [tok][128] f16 = K - c_k ;
// aq[tok] = c_q*128*QSC ; ck[tok] = c_k ; vT: [b][e][n] f16.
__global__ __launch_bounds__(256) void qkv_proj(const float* __restrict__ x,
                                                const _Float16* __restrict__ whiT,
                                                const _Float16* __restrict__ wloT,
                                                _Float16* __restrict__ q,
                                                _Float16* __restrict__ k,
                                                _Float16* __restrict__ vT,
                                                float* __restrict__ aq,
                                                float* __restrict__ ck) {
    const int widx = blockIdx.x >> 9;          // 0,1,2
    const int blk  = blockIdx.x & 511;
    const int lane = threadIdx.x & 63;
    const int wave = threadIdx.x >> 6;
    const int g    = lane >> 4;
    const int lr   = lane & 15;
    const int rb   = blk * 64 + wave * 16;

    h16x8 xhi[4], xlo[4];
    {
        const float* xrow = x + (size_t)(rb + lr) * EMB;
        #pragma unroll
        for (int kc = 0; kc < 4; ++kc) {
            const float* p = xrow + kc * 32 + g * 8;
            h16x8 ah, al;
            #pragma unroll
            for (int j = 0; j < 8; ++j) {
                float v = p[j];
                _Float16 h = (_Float16)v;
                ah[j] = h;
                al[j] = (_Float16)(v - (float)h);
            }
            xhi[kc] = ah;
            if (widx < 2) xlo[kc] = al;
        }
    }

    const int b  = rb >> 12;
    const int n0 = rb & 4095;

    f32x4 acc[8];
    #pragma unroll
    for (int ct = 0; ct < 8; ++ct) acc[ct] = (f32x4){0.f, 0.f, 0.f, 0.f};

    const _Float16* wh = whiT + (size_t)widx * 16384;
    const _Float16* wl = wloT + (size_t)widx * 16384;
    #pragma unroll
    for (int kc = 0; kc < 4; ++kc) {
        #pragma unroll
        for (int ct = 0; ct < 8; ++ct) {
            size_t off = (size_t)(ct * 16 + lr) * 128 + kc * 32 + g * 8;
            h16x8 bh = *(const h16x8*)(wh + off);
            acc[ct] = __builtin_amdgcn_mfma_f32_16x16x32_f16(xhi[kc], bh, acc[ct], 0, 0, 0);
            if (widx < 2) {
                h16x8 bl = *(const h16x8*)(wl + off);
                acc[ct] = __builtin_amdgcn_mfma_f32_16x16x32_f16(xlo[kc], bh, acc[ct], 0, 0, 0);
                acc[ct] = __builtin_amdgcn_mfma_f32_16x16x32_f16(xhi[kc], bl, acc[ct], 0, 0, 0);
            }
        }
    }

    if (widx < 2) {
        float c[4];
        #pragma unroll
        for (int r = 0; r < 4; ++r) {
            float rs = 0.f;
            #pragma unroll
            for (int ct = 0; ct < 8; ++ct) rs += acc[ct][r];
            #pragma unroll
            for (int off = 8; off; off >>= 1) rs += __shfl_xor(rs, off);
            c[r] = rs * (1.0f / 128.0f);
        }
        if (widx == 0) {
            #pragma unroll
            for (int ct = 0; ct < 8; ++ct)
                #pragma unroll
                for (int r = 0; r < 4; ++r) {
                    size_t row = rb + g * 4 + r;
                    q[row * 128 + ct * 16 + lr] = (_Float16)((acc[ct][r] - c[r]) * QSC);
                }
            if (lr == 0) {
                #pragma unroll
                for (int r = 0; r < 4; ++r) aq[rb + g * 4 + r] = c[r] * 128.0f * QSC;
            }
        } else {
            #pragma unroll
            for (int ct = 0; ct < 8; ++ct)
                #pragma unroll
                for (int r = 0; r < 4; ++r) {
                    size_t row = rb + g * 4 + r;
                    k[row * 128 + ct * 16 + lr] = (_Float16)(acc[ct][r] - c[r]);
                }
            if (lr == 0) {
                #pragma unroll
                for (int r = 0; r < 4; ++r) ck[rb + g * 4 + r] = c[r];
            }
        }
    } else {
        #pragma unroll
        for (int ct = 0; ct < 8; ++ct)
            #pragma unroll
            for (int r = 0; r < 4; ++r) {
                int e  = ct * 16 + lr;
                int nn = n0 + g * 4 + r;
                vT[((size_t)b * EMB + e) * NSEQ + nn] = (_Float16)acc[ct][r];
            }
    }
}

// ---------------- flash attention ----------------
// r4's proven pipeline (K AND V LDS-staged, prefetch t+1 issued before compute(t),
// one barrier/tile) + swapped QK^T with permuted K slots + in-register P +
// per-lane scalar softmax (exp2 domain, deferred l, defer-max).
// K slot: sigma(kv) = (2*(kv>>5) + ((kv>>2)&1))*16 + ((kv>>3)&3)*4 + (kv&3)
// -> lane (g,lr) owns P[q=lr][kv in w*32+g*8..+7] = PV A-fragment directly.
__global__ __launch_bounds__(256) void flash(const _Float16* __restrict__ q,
                                             const _Float16* __restrict__ k,
                                             const _Float16* __restrict__ vT,
                                             const float* __restrict__ aq,
                                             const float* __restrict__ ck,
                                             float* __restrict__ out) {
    __shared__ __align__(16) char KsB[2][16384];   // 64 slots x 256 B, XOR-swizzled
    __shared__ __align__(16) char VsB[2][16384];   // 128 rows x 128 B, XOR-swizzled

    // bijective XCD swizzle: each XCD owns one batch
    const int bp  = blockIdx.x;
    const int bid = (bp & 7) * 64 + (bp >> 3);

    const int lane = threadIdx.x & 63;
    const int wave = threadIdx.x >> 6;
    const int g    = lane >> 4;
    const int lr   = lane & 15;
    const int b    = bid >> 6;
    const int qt   = bid & 63;
    const size_t qtok = (size_t)b * NSEQ + qt * 64 + wave * 16;

    const _Float16* kbat = k  + (size_t)b * NSEQ * EMB;
    const _Float16* vbat = vT + (size_t)b * EMB * NSEQ;
    const float*    ckb  = ck + (size_t)b * NSEQ;

    // Q fragments (QSC folded); per-lane softmax row is q = lr
    h16x8 qf[4];
    #pragma unroll
    for (int kc = 0; kc < 4; ++kc)
        qf[kc] = *(const h16x8*)(q + (qtok + lr) * 128 + kc * 32 + g * 8);
    const float aqv = aq[qtok + lr];

    // K staging geometry: global row r64 -> permuted LDS slot
    const int r64   = wave * 16 + (lane >> 2);
    const int kcolB = (lane & 3) * 64;
    const int kslot = ((r64 >> 5) * 2 + ((r64 >> 2) & 1)) * 16 + (((r64 >> 3) & 3) << 2) + (r64 & 3);
    const char* kp = (const char*)(kbat + (size_t)r64 * EMB) + kcolB;   // +16384 B/tile
    const int kdst = kslot * 256;
    const int kswz = (kslot & 15) << 4;

    // V staging geometry: 128 rows (e) x 128 B
    const int vrow  = wave * 32 + (lane >> 1);
    const int vcolB = (lane & 1) * 64;
    const char* vp = (const char*)(vbat + (size_t)vrow * NSEQ) + vcolB;  // +128 B/tile
    const int vdst = vrow * 128;
    const int vswz = (vrow & 7) << 4;

    h16x8 stK[4], stV[4];
    // prologue: stage tile 0
    #pragma unroll
    for (int i = 0; i < 4; ++i) stK[i] = *(const h16x8*)(kp + i * 16);
    #pragma unroll
    for (int i = 0; i < 4; ++i) stV[i] = *(const h16x8*)(vp + i * 16);
    #pragma unroll
    for (int i = 0; i < 4; ++i)
        *(h16x8*)(KsB[0] + kdst + ((kcolB + i * 16) ^ kswz)) = stK[i];
    #pragma unroll
    for (int i = 0; i < 4; ++i)
        *(h16x8*)(VsB[0] + vdst + ((vcolB + i * 16) ^ vswz)) = stV[i];
    __syncthreads();

    f32x4 o[8];
    #pragma unroll
    for (int ct = 0; ct < 8; ++ct) o[ct] = (f32x4){0.f, 0.f, 0.f, 0.f};
    float m = -1e30f;
    float l = 0.f;     // per-lane partial row sum for q = lr

    int cur = 0;
    for (int t = 0; t < NT; ++t) {
        // (1) issue next tile's staging loads — whole compute phase hides latency
        kp += 16384; vp += 128;
        if (t + 1 < NT) {
            #pragma unroll
            for (int i = 0; i < 4; ++i) stK[i] = *(const h16x8*)(kp + i * 16);
            #pragma unroll
            for (int i = 0; i < 4; ++i) stV[i] = *(const h16x8*)(vp + i * 16);
        }

        // (2) rank-1 coefficients, permuted to slot ownership
        f32x4 ckt[4];
        #pragma unroll
        for (int ct = 0; ct < 4; ++ct)
            ckt[ct] = *(const f32x4*)(ckb + t * 64 + (ct >> 1) * 32 + (ct & 1) * 4 + g * 8);

        // (3) S^T = mfma(K, Q): lane holds S[q=lr][kv=(ct>>1)*32 + g*8 + (ct&1)*4 + r]
        const char* Kb = KsB[cur];
        f32x4 s[4];
        __builtin_amdgcn_s_setprio(1);
        #pragma unroll
        for (int ct = 0; ct < 4; ++ct) {
            f32x4 acc = (f32x4){0.f, 0.f, 0.f, 0.f};
            #pragma unroll
            for (int kc = 0; kc < 4; ++kc) {
                h16x8 kb = *(const h16x8*)(Kb + (ct * 16 + lr) * 256 + ((kc * 64 + g * 16) ^ (lr << 4)));
                acc = __builtin_amdgcn_mfma_f32_16x16x32_f16(kb, qf[kc], acc, 0, 0, 0);
            }
            #pragma unroll
            for (int r = 0; r < 4; ++r) acc[r] += aqv * ckt[ct][r];
            s[ct] = acc;
        }
        __builtin_amdgcn_s_setprio(0);

        // (4) per-lane softmax (log2 domain, defer-max, deferred l)
        float tm = s[0][0];
        #pragma unroll
        for (int ct = 0; ct < 4; ++ct)
            #pragma unroll
            for (int r = 0; r < 4; ++r) tm = fmaxf(tm, s[ct][r]);
        tm = fmaxf(tm, __shfl_xor(tm, 16));
        tm = fmaxf(tm, __shfl_xor(tm, 32));
        if (__any(tm > m + 11.544f)) {
            float mn = fmaxf(m, tm);
            float sc = exp2f(m - mn);
            m = mn;
            l *= sc;
            float oscr[4];
            #pragma unroll
            for (int r = 0; r < 4; ++r)
                oscr[r] = __shfl(sc, (lane & 48) | (g * 4 + r));
            #pragma unroll
            for (int ct = 0; ct < 8; ++ct)
                #pragma unroll
                for (int r = 0; r < 4; ++r) o[ct][r] *= oscr[r];
        }
        #pragma unroll
        for (int ct = 0; ct < 4; ++ct)
            #pragma unroll
            for (int r = 0; r < 4; ++r) {
                float pv = exp2f(s[ct][r] - m);
                s[ct][r] = pv;
                l += pv;
            }

        // (5) pack P into PV A-fragments (lane-local, no LDS)
        h16x8 pa[2];
        #pragma unroll
        for (int w = 0; w < 2; ++w) {
            h16x8 t8;
            #pragma unroll
            for (int j = 0; j < 4; ++j) {
                t8[j]     = (_Float16)s[2 * w][j];
                t8[4 + j] = (_Float16)s[2 * w + 1][j];
            }
            pa[w] = t8;
        }

        // (6) O += P V  (V B-frags from swizzled LDS)
        const char* Vb = VsB[cur];
        __builtin_amdgcn_s_setprio(1);
        #pragma unroll
        for (int ct = 0; ct < 8; ++ct) {
            #pragma unroll
            for (int w = 0; w < 2; ++w) {
                h16x8 vb = *(const h16x8*)(Vb + (ct * 16 + lr) * 128 + ((w * 64 + g * 16) ^ ((lr & 7) << 4)));
                o[ct] = __builtin_amdgcn_mfma_f32_16x16x32_f16(pa[w], vb, o[ct], 0, 0, 0);
            }
        }
        __builtin_amdgcn_s_setprio(0);

        // (7) write next tile into the other buffer; one barrier per tile
        if (t + 1 < NT) {
            char* kw = (char*)KsB[cur ^ 1];
            char* vw = (char*)VsB[cur ^ 1];
            #pragma unroll
            for (int i = 0; i < 4; ++i)
                *(h16x8*)(kw + kdst + ((kcolB + i * 16) ^ kswz)) = stK[i];
            #pragma unroll
            for (int i = 0; i < 4; ++i)
                *(h16x8*)(vw + vdst + ((vcolB + i * 16) ^ vswz)) = stV[i];
        }
        __syncthreads();
        cur ^= 1;
    }

    // epilogue: finish row sum for q=lr, broadcast 1/l to O-row owners
    l += __shfl_xor(l, 16);
    l += __shfl_xor(l, 32);
    float linv = 1.0f / l;
    float lrw[4];
    #pragma unroll
    for (int r = 0; r < 4; ++r)
        lrw[r] = __shfl(linv, (lane & 48) | (g * 4 + r));
    #pragma unroll
    for (int ct = 0; ct < 8; ++ct)
        #pragma unroll
        for (int r = 0; r < 4; ++r) {
            size_t row = qtok + g * 4 + r;
            out[row * EMB + ct * 16 + lr] = o[ct][r] * lrw[r];
        }
}

extern "C" void kernel_launch(void* const* d_in, const int* in_sizes, int n_in,
                              void* d_out, int out_size, void* d_ws, size_t ws_size,
                              hipStream_t stream) {
    const float* x  = (const float*)d_in[0];
    const float* wq = (const float*)d_in[1];
    const float* wk = (const float*)d_in[2];
    const float* wv = (const float*)d_in[3];

    char* ws = (char*)d_ws;
    _Float16* q    = (_Float16*)(ws);                          // 8 MB
    _Float16* kk   = (_Float16*)(ws + 8388608);                // 8 MB
    _Float16* vT   = (_Float16*)(ws + 16777216);               // 8 MB
    float*    aq   = (float*)   (ws + 25165824);               // 128 KB
    float*    ck   = (float*)   (ws + 25296896);               // 128 KB
    _Float16* whiT = (_Float16*)(ws + 25427968);               // 96 KB
    _Float16* wloT = (_Float16*)(ws + 25526272);               // 96 KB

    prep_w<<<192, 256, 0, stream>>>(wq, wk, wv, whiT, wloT);
    qkv_proj<<<1536, 256, 0, stream>>>(x, whiT, wloT, q, kk, vT, aq, ck);
    flash<<<512, 256, 0, stream>>>(q, kk, vT, aq, ck, (float*)d_out);
}